// Round 18
// baseline (302.622 us; speedup 1.0000x reference)
//
#include <hip/hip_runtime.h>
#include <cstdint>
#include <cstddef>

#define Bn 64
#define Tn 2048
#define Un 512
#define QSn 512
#define MSn 512
#define TCH 32
#define NCH 64   // chunks per batch = Tn/TCH
#define NKT 16   // K-tiles: 512 / 32

using f32x16 = __attribute__((ext_vector_type(16))) float;
using bf16x8 = __attribute__((ext_vector_type(8))) short;

__device__ __forceinline__ unsigned short f2bf(float x) {
    unsigned int u = __float_as_uint(x);
    u += 0x7FFFu + ((u >> 16) & 1u);
    return (unsigned short)(u >> 16);
}

__device__ __forceinline__ unsigned int pk2bf(float lo, float hi) {
    unsigned int r;
    asm("v_cvt_pk_bf16_f32 %0, %1, %2" : "=v"(r) : "v"(lo), "v"(hi));
    return r;
}

__device__ __forceinline__ bf16x8 cvt8(float4 a, float4 b) {
    union { unsigned int u[4]; bf16x8 v; } r;
    r.u[0] = pk2bf(a.x, a.y);
    r.u[1] = pk2bf(a.z, a.w);
    r.u[2] = pk2bf(b.x, b.y);
    r.u[3] = pk2bf(b.z, b.w);
    return r.v;
}

__device__ __forceinline__ float tanh_fast(float x) {
    float e = exp2f(x * 2.885390043258667f);   // e^{2x}
    return 1.f - 2.f * __builtin_amdgcn_rcpf(e + 1.f);
}

// async global->LDS, 16B per lane; LDS dest = wave-uniform base + lane*16
#define GLOAD(G, L) __builtin_amdgcn_global_load_lds( \
    (const __attribute__((address_space(1))) void*)(G), \
    (__attribute__((address_space(3))) void*)(L), 16, 0, 0)

#define SB() __builtin_amdgcn_sched_barrier(0)

// ---------------- Wm f32 -> bf16 pre-convert ----------------
__global__ __launch_bounds__(256) void cvt_kernel(const float* __restrict__ src,
                                                  unsigned short* __restrict__ dst) {
    int i = blockIdx.x * 256 + threadIdx.x;  // one float4 per thread
    float4 v = *(const float4*)(src + (size_t)i * 4);
    ushort4 h = { f2bf(v.x), f2bf(v.y), f2bf(v.z), f2bf(v.w) };
    *(ushort4*)&dst[(size_t)i * 4] = h;
}

// ---------------- pq = query @ Wq^T : [B,U] ----------------
__global__ __launch_bounds__(128) void pq_kernel(const float* __restrict__ query,
                                                 const float* __restrict__ Wq,
                                                 float* __restrict__ pq) {
    __shared__ float ql[QSn];
    const int b = blockIdx.x;
    const int quad = blockIdx.y;
    const int tid = threadIdx.x;
    for (int i = tid; i < QSn; i += 128) ql[i] = query[(size_t)b * QSn + i];
    __syncthreads();
    const int u = quad * 128 + tid;
    const float* w = Wq + (size_t)u * QSn;
    float a0 = 0.f, a1 = 0.f;
    #pragma unroll 4
    for (int k = 0; k < QSn; k += 8) {
        float4 w0 = *(const float4*)(w + k);
        float4 w1 = *(const float4*)(w + k + 4);
        float4 q0 = *(const float4*)(ql + k);
        float4 q1 = *(const float4*)(ql + k + 4);
        a0 += w0.x * q0.x + w0.y * q0.y + w0.z * q0.z + w0.w * q0.w;
        a1 += w1.x * q1.x + w1.y * q1.y + w1.z * q1.z + w1.w * q1.w;
    }
    pq[(size_t)b * Un + u] = a0 + a1;
}

// ---------------- fused score+softmax+context (v18: barrier-free k-loop) ----
// Block = (b, 32-t chunk), 512 thr = 8 waves. Wave w owns u [w*64, w*64+64):
// acc[2] = ONE 32x32 m-frag x 2 n-frags = 32 AGPR.
// ALL operands wave-private in LDS (each wave its own A copy; 7/8 of A reads
// are L2 hits, keys leave HBM once):
//   A: keys f32 32x32 (4 KB), 4 GLOADs, rowpair-XOR layout (f32 granules).
//   B: Wm bf16 64x32 (4 KB), 4 GLOADs, R16-verbatim zero-conflict layout.
// Per kt (NO BARRIER): vmcnt(0) -> ds_reads(kt)+cvt -> lgkmcnt(0) [reads
// returned => overwrite WAR-safe wave-locally] -> issue GLOAD A/B(kt+1) ->
// MFMA(kt) pure-reg overlapping the loads. 16 self-paced streams per CU.
__global__ __launch_bounds__(512, 4) void fused_kernel(const float* __restrict__ keys,
                                                       const unsigned short* __restrict__ WmB,
                                                       const float* __restrict__ pq,
                                                       const float* __restrict__ Wa,
                                                       float* __restrict__ score_out,
                                                       float* __restrict__ pm,
                                                       float* __restrict__ pl,
                                                       float* __restrict__ pctx) {
    __shared__ __align__(16) float Ah[8][TCH * 32];             // 32 KB f32
    __shared__ __align__(16) unsigned short Bh[8][64 * 32];     // 32 KB bf16
    __shared__ float sc_lds[8][TCH];                            // 1 KB
    __shared__ float stot[TCH];
    __shared__ float wexp[TCH];

    const int tid = threadIdx.x;
    const int lane = tid & 63;
    const int w = tid >> 6;
    const int lc = lane & 31;
    const int l5 = lane >> 5;
    const int b = blockIdx.y;
    const int chunk = blockIdx.x;
    const int t0 = chunk * TCH;

    const float* keyBase = keys + (size_t)(b * Tn + t0) * MSn;

    // ---- A GLOAD source offsets (swizzle folded into source address).
    // instr j, lane l -> linear dest (j*1024 + l*16) bytes = rowpair
    // rp = j*4 + (l>>4), phys granule = l&15 (16B of 4 f32).
    // logical g = phys ^ (rp&7); row = rp*2 + (g&1); kgran = g>>1.
    int aoff[4];
    #pragma unroll
    for (int j = 0; j < 4; ++j) {
        int rp = j * 4 + (lane >> 4);
        int g = (lane & 15) ^ (rp & 7);
        aoff[j] = (rp * 2 + (g & 1)) * MSn + (g >> 1) * 4;
    }

    // ---- B GLOAD source (R16-verbatim zero-conflict swizzle)
    const int bg = (lane & 7) ^ ((lane >> 3) & 7);
    const unsigned short* gBw = WmB +
        (size_t)(w * 64 + (((lane >> 3) << 1) | (bg & 1))) * MSn + (bg >> 1) * 8;

    #define STAGE_A(KT) do { \
        char* aD_ = (char*)&Ah[w][0]; \
        GLOAD(keyBase + (KT) * 32 + aoff[0], aD_); \
        GLOAD(keyBase + (KT) * 32 + aoff[1], aD_ + 1024); \
        GLOAD(keyBase + (KT) * 32 + aoff[2], aD_ + 2048); \
        GLOAD(keyBase + (KT) * 32 + aoff[3], aD_ + 3072); } while (0)

    #define STAGE_B(KT) do { \
        const unsigned short* gb_ = gBw + (KT) * 32; \
        char* bD_ = (char*)&Bh[w][0]; \
        GLOAD(gb_,                    bD_); \
        GLOAD(gb_ + (size_t)16 * MSn, bD_ + 1024); \
        GLOAD(gb_ + (size_t)32 * MSn, bD_ + 2048); \
        GLOAD(gb_ + (size_t)48 * MSn, bD_ + 3072); } while (0)

    f32x16 acc[2];
    #pragma unroll
    for (int nf = 0; nf < 2; ++nf)
        #pragma unroll
        for (int r = 0; r < 16; ++r) acc[nf][r] = 0.f;

    // ---- prologue: pq/Wa regs; stage kt=0 (no barrier!)
    float pqv[2], wav[2];
    #pragma unroll
    for (int nf = 0; nf < 2; ++nf) {
        int u = w * 64 + nf * 32 + lc;
        pqv[nf] = pq[(size_t)b * Un + u];
        wav[nf] = Wa[u];
    }
    SB();
    STAGE_A(0);
    STAGE_B(0);
    SB();

    #pragma unroll
    for (int kt = 0; kt < NKT; ++kt) {
        // 1) all wave-local staging of kt landed
        asm volatile("s_waitcnt vmcnt(0)" ::: "memory");
        SB();

        // 2) ds_reads for kt + cvt of A
        bf16x8 af[2], bfr[2][2];
        {
            const float* lA = &Ah[w][0];
            const unsigned short* lB = &Bh[w][0];
            #pragma unroll
            for (int ks = 0; ks < 2; ++ks) {
                int rp = lc >> 1;
                int kg0 = (ks * 2 + l5) * 2;
                int g0 = (kg0 << 1) | (lc & 1);
                int g1 = ((kg0 + 1) << 1) | (lc & 1);
                float4 f0 = *(const float4*)&lA[rp * 64 + (g0 ^ (rp & 7)) * 4];
                float4 f1 = *(const float4*)&lA[rp * 64 + (g1 ^ (rp & 7)) * 4];
                af[ks] = cvt8(f0, f1);
                #pragma unroll
                for (int nf = 0; nf < 2; ++nf) {
                    int lr = nf * 32 + lc;
                    int gp = (((ks * 2 + l5) << 1) | (lr & 1)) ^ ((lr >> 1) & 7);
                    bfr[ks][nf] = *(const bf16x8*)&lB[(lr >> 1) * 64 + gp * 8];
                }
            }
        }
        // 3) reads returned -> safe to overwrite our private buffers
        asm volatile("s_waitcnt lgkmcnt(0)" ::: "memory");
        SB();
        if (kt < NKT - 1) {
            STAGE_A(kt + 1);
            STAGE_B(kt + 1);
            SB();
        }

        // 4) MFMA(kt): pure-register, overlaps the in-flight loads
        #pragma unroll
        for (int ks = 0; ks < 2; ++ks) {
            acc[0] = __builtin_amdgcn_mfma_f32_32x32x16_bf16(af[ks], bfr[ks][0], acc[0], 0, 0, 0);
            acc[1] = __builtin_amdgcn_mfma_f32_32x32x16_bf16(af[ks], bfr[ks][1], acc[1], 0, 0, 0);
        }
    }
    #undef STAGE_A
    #undef STAGE_B

    // ---- epilogue: per-wave partial score over its 64 u
    // C layout (32x32): col(u) = lc, row(t) = (r&3) + 8*(r>>2) + 4*l5
    #pragma unroll
    for (int r = 0; r < 16; ++r) {
        float s = tanh_fast(acc[0][r] + pqv[0]) * wav[0]
                + tanh_fast(acc[1][r] + pqv[1]) * wav[1];
        s += __shfl_xor(s, 16);
        s += __shfl_xor(s, 8);
        s += __shfl_xor(s, 4);
        s += __shfl_xor(s, 2);
        s += __shfl_xor(s, 1);
        if (lc == 0)
            sc_lds[w][(r & 3) + 8 * (r >> 2) + 4 * l5] = s;
    }
    __syncthreads();

    // ---- combine 8 wave-partials; write raw scores
    if (tid < TCH) {
        float v = ((sc_lds[0][tid] + sc_lds[1][tid]) + (sc_lds[2][tid] + sc_lds[3][tid]))
                + ((sc_lds[4][tid] + sc_lds[5][tid]) + (sc_lds[6][tid] + sc_lds[7][tid]));
        stot[tid] = v;
        score_out[(size_t)b * Tn + t0 + tid] = v;
    }
    __syncthreads();

    // ---- chunk softmax partials (32 values, lanes 0..31 of wave 0)
    if (tid < TCH) {
        float v = stot[tid];
        float mx = v;
        #pragma unroll
        for (int off = 16; off; off >>= 1) mx = fmaxf(mx, __shfl_xor(mx, off));
        float e = __expf(v - mx);
        wexp[tid] = e;
        float sum = e;
        #pragma unroll
        for (int off = 16; off; off >>= 1) sum += __shfl_xor(sum, off);
        if (tid == 0) {
            pm[b * NCH + chunk] = mx;
            pl[b * NCH + chunk] = sum;
        }
    }
    __syncthreads();

    // ---- ctx partial: thread owns 1 m-col; keys rows re-read (L2-hot)
    const float* kp = keyBase + tid;
    float cx = 0.f;
    #pragma unroll 8
    for (int t = 0; t < TCH; ++t)
        cx += wexp[t] * kp[(size_t)t * MSn];
    pctx[((size_t)(b * NCH + chunk)) * MSn + tid] = cx;
}

// ---------------- merge chunk partials -> total_context ----------------
__global__ __launch_bounds__(512) void merge_kernel(const float* __restrict__ pm,
                                                    const float* __restrict__ pl,
                                                    const float* __restrict__ pctx,
                                                    float* __restrict__ ctx) {
    __shared__ float sm[NCH], sl[NCH];
    const int b = blockIdx.x, tid = threadIdx.x;
    if (tid < NCH) {
        sm[tid] = pm[b * NCH + tid];
        sl[tid] = pl[b * NCH + tid];
    }
    __syncthreads();
    float M = -1e30f;
    #pragma unroll
    for (int c = 0; c < NCH; ++c) M = fmaxf(M, sm[c]);
    float L = 0.f;
    #pragma unroll
    for (int c = 0; c < NCH; ++c) L += sl[c] * __expf(sm[c] - M);
    const float inv = 1.f / L;
    float acc = 0.f;
    #pragma unroll
    for (int c = 0; c < NCH; ++c)
        acc += __expf(sm[c] - M) * pctx[((size_t)(b * NCH + c)) * MSn + tid];
    ctx[(size_t)b * MSn + tid] = acc * inv;
}

extern "C" void kernel_launch(void* const* d_in, const int* in_sizes, int n_in,
                              void* d_out, int out_size, void* d_ws, size_t ws_size,
                              hipStream_t stream) {
    const float* query = (const float*)d_in[0];
    const float* keys  = (const float*)d_in[1];
    const float* Wq    = (const float*)d_in[2];
    const float* Wm    = (const float*)d_in[3];
    const float* Wa    = (const float*)d_in[4];

    float* ctx_out   = (float*)d_out;                    // [64][512]
    float* score_out = (float*)d_out + (size_t)Bn * MSn; // [64][2048]

    char* ws = (char*)d_ws;
    float* ws_pq   = (float*)(ws);                       // 128 KB
    unsigned short* ws_wmbf = (unsigned short*)(ws + 131072);  // 512 KB
    float* ws_pm   = (float*)(ws + 655360);              // 16 KB
    float* ws_pl   = (float*)(ws + 671744);              // 16 KB
    float* ws_pctx = (float*)(ws + 688128);              // 8 MB [64][64][512]

    cvt_kernel<<<(Un * MSn / 4) / 256, 256, 0, stream>>>(Wm, ws_wmbf);
    pq_kernel<<<dim3(Bn, 4), 128, 0, stream>>>(query, Wq, ws_pq);
    fused_kernel<<<dim3(NCH, Bn), 512, 0, stream>>>(keys, ws_wmbf, ws_pq, Wa,
                                                    score_out, ws_pm, ws_pl, ws_pctx);
    merge_kernel<<<Bn, 512, 0, stream>>>(ws_pm, ws_pl, ws_pctx, ctx_out);
}

// Round 19
// 221.233 us; speedup vs baseline: 1.3679x; 1.3679x over previous
//
#include <hip/hip_runtime.h>
#include <cstdint>
#include <cstddef>

#define Bn 64
#define Tn 2048
#define Un 512
#define QSn 512
#define MSn 512
#define TCH 64
#define NCH 32   // chunks per batch = Tn/TCH
#define NKT 16   // K-tiles: 512 / 32

using f32x16 = __attribute__((ext_vector_type(16))) float;
using bf16x8 = __attribute__((ext_vector_type(8))) short;

__device__ __forceinline__ unsigned short f2bf(float x) {
    unsigned int u = __float_as_uint(x);
    u += 0x7FFFu + ((u >> 16) & 1u);
    return (unsigned short)(u >> 16);
}

__device__ __forceinline__ unsigned int pk2bf(float lo, float hi) {
    unsigned int r;
    asm("v_cvt_pk_bf16_f32 %0, %1, %2" : "=v"(r) : "v"(lo), "v"(hi));
    return r;
}

__device__ __forceinline__ float tanh_fast(float x) {
    float e = exp2f(x * 2.885390043258667f);   // e^{2x}
    return 1.f - 2.f * __builtin_amdgcn_rcpf(e + 1.f);
}

// async global->LDS, 16B per lane; LDS dest = wave-uniform base + lane*16
#define GLOAD(G, L) __builtin_amdgcn_global_load_lds( \
    (const __attribute__((address_space(1))) void*)(G), \
    (__attribute__((address_space(3))) void*)(L), 16, 0, 0)

#define SB() __builtin_amdgcn_sched_barrier(0)

// ---------------- Wm f32 -> bf16 pre-convert ----------------
__global__ __launch_bounds__(256) void cvt_kernel(const float* __restrict__ src,
                                                  unsigned short* __restrict__ dst) {
    int i = blockIdx.x * 256 + threadIdx.x;  // one float4 per thread
    float4 v = *(const float4*)(src + (size_t)i * 4);
    ushort4 h = { f2bf(v.x), f2bf(v.y), f2bf(v.z), f2bf(v.w) };
    *(ushort4*)&dst[(size_t)i * 4] = h;
}

// ---------------- pq = query @ Wq^T : [B,U] ----------------
__global__ __launch_bounds__(128) void pq_kernel(const float* __restrict__ query,
                                                 const float* __restrict__ Wq,
                                                 float* __restrict__ pq) {
    __shared__ float ql[QSn];
    const int b = blockIdx.x;
    const int quad = blockIdx.y;
    const int tid = threadIdx.x;
    for (int i = tid; i < QSn; i += 128) ql[i] = query[(size_t)b * QSn + i];
    __syncthreads();
    const int u = quad * 128 + tid;
    const float* w = Wq + (size_t)u * QSn;
    float a0 = 0.f, a1 = 0.f;
    #pragma unroll 4
    for (int k = 0; k < QSn; k += 8) {
        float4 w0 = *(const float4*)(w + k);
        float4 w1 = *(const float4*)(w + k + 4);
        float4 q0 = *(const float4*)(ql + k);
        float4 q1 = *(const float4*)(ql + k + 4);
        a0 += w0.x * q0.x + w0.y * q0.y + w0.z * q0.z + w0.w * q0.w;
        a1 += w1.x * q1.x + w1.y * q1.y + w1.z * q1.z + w1.w * q1.w;
    }
    pq[(size_t)b * Un + u] = a0 + a1;
}

// ---------------- fused score+softmax+context (v19: A-resident, 0-barrier) --
// Block = (b, 64-t chunk), 512 thr = 8 waves, wave w owns u [w*64, w*64+64):
// acc[2][2] = 64 AGPR.
// A: keys 64t x 512k bf16 (64 KB) staged ONCE at block start (reg-pipelined
//    f32 loads in groups of 4 k-blocks -> cvt_pk -> zero-conflict LDS layout),
//    one __syncthreads. Read-only thereafter.
// B: Wm bf16, WAVE-PRIVATE dbuf (reads = own writes; R16 zero-conflict
//    swizzle), GLOADed 1 kt ahead, counted vmcnt(4) -> one-period slack.
// K-LOOP HAS NO BARRIERS AND NO LGKM STALLS: single latency class (B),
// 8 self-paced wave streams per CU. LDS 130 KB -> 1 block/CU.
__global__ __launch_bounds__(512, 2) void fused_kernel(const float* __restrict__ keys,
                                                       const unsigned short* __restrict__ WmB,
                                                       const float* __restrict__ pq,
                                                       const float* __restrict__ Wa,
                                                       float* __restrict__ score_out,
                                                       float* __restrict__ pm,
                                                       float* __restrict__ pl,
                                                       float* __restrict__ pctx) {
    __shared__ __align__(16) unsigned short Ah[NKT * TCH * 32];  // 64 KB
    __shared__ __align__(16) unsigned short Bh[2][512 * 32];     // 64 KB
    __shared__ float sc_lds[8][TCH];                             // 2 KB
    __shared__ float stot[TCH];
    __shared__ float wexp[TCH];

    const int tid = threadIdx.x;
    const int lane = tid & 63;
    const int w = tid >> 6;
    const int lc = lane & 31;
    const int l5 = lane >> 5;
    const int b = blockIdx.y;
    const int chunk = blockIdx.x;
    const int t0 = chunk * TCH;

    // ---- A staging geometry (R16-verbatim per 32k-block): thread (ar, kq)
    const int ar = tid >> 3;          // 0..63
    const int kq = tid & 7;           // 4 f32 at k = kq*4 within the 32k block
    const int awof = (ar >> 1) * 64 +
                     (((((kq >> 1) << 1) | (ar & 1)) ^ ((ar >> 1) & 7)) * 8) +
                     (kq & 1) * 4;
    const float* gA = keys + ((size_t)b * Tn + t0 + ar) * MSn + kq * 4;

    // ---- B staging source (R16-verbatim zero-conflict swizzle, wave rows)
    const int bg = (lane & 7) ^ ((lane >> 3) & 7);
    const unsigned short* gBw = WmB +
        (size_t)(w * 64 + (((lane >> 3) << 1) | (bg & 1))) * MSn + (bg >> 1) * 8;

    #define STAGE_B(KT, BUF) do { \
        const unsigned short* gb_ = gBw + (KT) * 32; \
        char* bD_ = (char*)&Bh[BUF][0] + w * 4096; \
        GLOAD(gb_,                    bD_); \
        GLOAD(gb_ + (size_t)16 * MSn, bD_ + 1024); \
        GLOAD(gb_ + (size_t)32 * MSn, bD_ + 2048); \
        GLOAD(gb_ + (size_t)48 * MSn, bD_ + 3072); } while (0)

    f32x16 acc[2][2];
    #pragma unroll
    for (int mf = 0; mf < 2; ++mf)
        #pragma unroll
        for (int nf = 0; nf < 2; ++nf)
            #pragma unroll
            for (int r = 0; r < 16; ++r) acc[mf][nf][r] = 0.f;

    // ---- pq/Wa into regs first (keeps them out of the staged FIFO region)
    float pqv[2], wav[2];
    #pragma unroll
    for (int nf = 0; nf < 2; ++nf) {
        int u = w * 64 + nf * 32 + lc;
        pqv[nf] = pq[(size_t)b * Un + u];
        wav[nf] = Wa[u];
    }
    SB();

    // ---- A prologue: 16 k-blocks, reg-pipelined in groups of 4
    {
        float4 f0[4], f1[4];
        #pragma unroll
        for (int j = 0; j < 4; ++j) f0[j] = *(const float4*)(gA + j * 32);
        #pragma unroll
        for (int g = 0; g < 4; ++g) {
            if (g < 3) {
                #pragma unroll
                for (int j = 0; j < 4; ++j)
                    f1[j] = *(const float4*)(gA + (g + 1) * 128 + j * 32);
            }
            #pragma unroll
            for (int j = 0; j < 4; ++j) {
                uint2 h;
                h.x = pk2bf(f0[j].x, f0[j].y);
                h.y = pk2bf(f0[j].z, f0[j].w);
                *(uint2*)&Ah[(g * 4 + j) * (TCH * 32) + awof] = h;
            }
            #pragma unroll
            for (int j = 0; j < 4; ++j) f0[j] = f1[j];
        }
    }
    // stage B(0) into buf 0, then one full-drain barrier (A visible to all)
    STAGE_B(0, 0);
    __syncthreads();

    // ---- barrier-free k-loop
    #pragma unroll
    for (int kt = 0; kt < NKT; ++kt) {
        if (kt < NKT - 1) {
            STAGE_B(kt + 1, (kt + 1) & 1);   // own buf; own reads of it done @kt-1
            SB();
            asm volatile("s_waitcnt vmcnt(4)" ::: "memory");  // B(kt) landed
        } else {
            asm volatile("s_waitcnt vmcnt(0)" ::: "memory");
        }
        SB();

        const unsigned short* lA = &Ah[kt * (TCH * 32)];
        const unsigned short* lB = &Bh[kt & 1][0];
        #pragma unroll
        for (int ks = 0; ks < 2; ++ks) {
            bf16x8 af[2], bfr[2];
            #pragma unroll
            for (int mf = 0; mf < 2; ++mf) {
                int r = mf * 32 + lc;
                int gp = (((ks * 2 + l5) << 1) | (r & 1)) ^ ((r >> 1) & 7);
                af[mf] = *(const bf16x8*)&lA[(r >> 1) * 64 + gp * 8];
            }
            #pragma unroll
            for (int nf = 0; nf < 2; ++nf) {
                int ru = w * 64 + nf * 32 + lc;
                int gp = (((ks * 2 + l5) << 1) | (ru & 1)) ^ ((ru >> 1) & 7);
                bfr[nf] = *(const bf16x8*)&lB[(ru >> 1) * 64 + gp * 8];
            }
            #pragma unroll
            for (int mf = 0; mf < 2; ++mf)
                #pragma unroll
                for (int nf = 0; nf < 2; ++nf)
                    acc[mf][nf] = __builtin_amdgcn_mfma_f32_32x32x16_bf16(
                        af[mf], bfr[nf], acc[mf][nf], 0, 0, 0);
        }
    }
    #undef STAGE_B

    // ---- epilogue: score = sum_u tanh(vals + pq[u]) * Wa[u]
    // C layout: col(u)=lc, row(t) = mf*32 + (r&3) + 8*(r>>2) + 4*l5
    #pragma unroll
    for (int mf = 0; mf < 2; ++mf) {
        #pragma unroll
        for (int r = 0; r < 16; ++r) {
            float s = tanh_fast(acc[mf][0][r] + pqv[0]) * wav[0]
                    + tanh_fast(acc[mf][1][r] + pqv[1]) * wav[1];
            s += __shfl_xor(s, 16);
            s += __shfl_xor(s, 8);
            s += __shfl_xor(s, 4);
            s += __shfl_xor(s, 2);
            s += __shfl_xor(s, 1);
            if (lc == 0)
                sc_lds[w][mf * 32 + (r & 3) + 8 * (r >> 2) + 4 * l5] = s;
        }
    }
    __syncthreads();
    if (tid < TCH) {
        float v = ((sc_lds[0][tid] + sc_lds[1][tid]) + (sc_lds[2][tid] + sc_lds[3][tid]))
                + ((sc_lds[4][tid] + sc_lds[5][tid]) + (sc_lds[6][tid] + sc_lds[7][tid]));
        stot[tid] = v;
        score_out[(size_t)b * Tn + t0 + tid] = v;
    }
    __syncthreads();

    // ---- chunk softmax partials on wave 0
    if (tid < 64) {
        float v = stot[tid];
        float mx = v;
        #pragma unroll
        for (int off = 32; off; off >>= 1) mx = fmaxf(mx, __shfl_xor(mx, off));
        float e = __expf(v - mx);
        wexp[tid] = e;
        float sum = e;
        #pragma unroll
        for (int off = 32; off; off >>= 1) sum += __shfl_xor(sum, off);
        if (tid == 0) {
            pm[b * NCH + chunk] = mx;
            pl[b * NCH + chunk] = sum;
        }
    }
    __syncthreads();

    // ---- ctx partial: thread owns 1 m-col; keys rows re-read (L2/L3-hot)
    const float* kp = keys + ((size_t)b * Tn + t0) * MSn + tid;
    float cx = 0.f;
    #pragma unroll 8
    for (int t = 0; t < TCH; ++t)
        cx += wexp[t] * kp[(size_t)t * MSn];
    pctx[((size_t)(b * NCH + chunk)) * MSn + tid] = cx;
}

// ---------------- merge chunk partials -> total_context ----------------
__global__ __launch_bounds__(512) void merge_kernel(const float* __restrict__ pm,
                                                    const float* __restrict__ pl,
                                                    const float* __restrict__ pctx,
                                                    float* __restrict__ ctx) {
    __shared__ float sm[NCH], sl[NCH];
    const int b = blockIdx.x, tid = threadIdx.x;
    if (tid < NCH) {
        sm[tid] = pm[b * NCH + tid];
        sl[tid] = pl[b * NCH + tid];
    }
    __syncthreads();
    float M = -1e30f;
    #pragma unroll
    for (int c = 0; c < NCH; ++c) M = fmaxf(M, sm[c]);
    float L = 0.f;
    #pragma unroll
    for (int c = 0; c < NCH; ++c) L += sl[c] * __expf(sm[c] - M);
    const float inv = 1.f / L;
    float acc = 0.f;
    #pragma unroll
    for (int c = 0; c < NCH; ++c)
        acc += __expf(sm[c] - M) * pctx[((size_t)(b * NCH + c)) * MSn + tid];
    ctx[(size_t)b * MSn + tid] = acc * inv;
}

extern "C" void kernel_launch(void* const* d_in, const int* in_sizes, int n_in,
                              void* d_out, int out_size, void* d_ws, size_t ws_size,
                              hipStream_t stream) {
    const float* query = (const float*)d_in[0];
    const float* keys  = (const float*)d_in[1];
    const float* Wq    = (const float*)d_in[2];
    const float* Wm    = (const float*)d_in[3];
    const float* Wa    = (const float*)d_in[4];

    float* ctx_out   = (float*)d_out;                    // [64][512]
    float* score_out = (float*)d_out + (size_t)Bn * MSn; // [64][2048]

    char* ws = (char*)d_ws;
    float* ws_pq   = (float*)(ws);                       // 128 KB
    unsigned short* ws_wmbf = (unsigned short*)(ws + 131072);  // 512 KB
    float* ws_pm   = (float*)(ws + 655360);              // 8 KB
    float* ws_pl   = (float*)(ws + 663552);              // 8 KB
    float* ws_pctx = (float*)(ws + 671744);              // 4 MB [64][32][512]

    cvt_kernel<<<(Un * MSn / 4) / 256, 256, 0, stream>>>(Wm, ws_wmbf);
    pq_kernel<<<dim3(Bn, 4), 128, 0, stream>>>(query, Wq, ws_pq);
    fused_kernel<<<dim3(NCH, Bn), 512, 0, stream>>>(keys, ws_wmbf, ws_pq, Wa,
                                                    score_out, ws_pm, ws_pl, ws_pctx);
    merge_kernel<<<Bn, 512, 0, stream>>>(ws_pm, ws_pl, ws_pctx, ctx_out);
}

// Round 20
// 219.050 us; speedup vs baseline: 1.3815x; 1.0100x over previous
//
#include <hip/hip_runtime.h>
#include <cstdint>
#include <cstddef>

#define Bn 64
#define Tn 2048
#define Un 512
#define QSn 512
#define MSn 512
#define TCH 64
#define NCH 32   // chunks per batch = Tn/TCH
#define NKT 16   // K-tiles: 512 / 32

using f32x16 = __attribute__((ext_vector_type(16))) float;
using bf16x8 = __attribute__((ext_vector_type(8))) short;

__device__ __forceinline__ unsigned short f2bf(float x) {
    unsigned int u = __float_as_uint(x);
    u += 0x7FFFu + ((u >> 16) & 1u);
    return (unsigned short)(u >> 16);
}

__device__ __forceinline__ unsigned int pk2bf(float lo, float hi) {
    unsigned int r;
    asm("v_cvt_pk_bf16_f32 %0, %1, %2" : "=v"(r) : "v"(lo), "v"(hi));
    return r;
}

__device__ __forceinline__ float b2f(unsigned short h) {
    return __uint_as_float(((unsigned int)h) << 16);
}

__device__ __forceinline__ float tanh_fast(float x) {
    float e = exp2f(x * 2.885390043258667f);   // e^{2x}
    return 1.f - 2.f * __builtin_amdgcn_rcpf(e + 1.f);
}

// async global->LDS, 16B per lane; LDS dest = wave-uniform base + lane*16
#define GLOAD(G, L) __builtin_amdgcn_global_load_lds( \
    (const __attribute__((address_space(1))) void*)(G), \
    (__attribute__((address_space(3))) void*)(L), 16, 0, 0)

#define SB() __builtin_amdgcn_sched_barrier(0)

// ---------------- Wm f32 -> bf16 pre-convert ----------------
__global__ __launch_bounds__(256) void cvt_kernel(const float* __restrict__ src,
                                                  unsigned short* __restrict__ dst) {
    int i = blockIdx.x * 256 + threadIdx.x;  // one float4 per thread
    float4 v = *(const float4*)(src + (size_t)i * 4);
    ushort4 h = { f2bf(v.x), f2bf(v.y), f2bf(v.z), f2bf(v.w) };
    *(ushort4*)&dst[(size_t)i * 4] = h;
}

// ---------------- keys f32 -> bf16 pre-convert (R8-exact, ~BW ceiling) ------
__global__ __launch_bounds__(256) void cvtkeys_kernel(const float* __restrict__ src,
                                                      unsigned short* __restrict__ dst) {
    size_t i = ((size_t)blockIdx.x * 256 + threadIdx.x) * 8;  // 8 f32 per thread
    float4 v0 = *(const float4*)(src + i);
    float4 v1 = *(const float4*)(src + i + 4);
    union { unsigned int u[4]; bf16x8 v; } h;
    h.u[0] = pk2bf(v0.x, v0.y);
    h.u[1] = pk2bf(v0.z, v0.w);
    h.u[2] = pk2bf(v1.x, v1.y);
    h.u[3] = pk2bf(v1.z, v1.w);
    *(bf16x8*)&dst[i] = h.v;
}

// ---------------- pq = query @ Wq^T : [B,U] ----------------
__global__ __launch_bounds__(128) void pq_kernel(const float* __restrict__ query,
                                                 const float* __restrict__ Wq,
                                                 float* __restrict__ pq) {
    __shared__ float ql[QSn];
    const int b = blockIdx.x;
    const int quad = blockIdx.y;
    const int tid = threadIdx.x;
    for (int i = tid; i < QSn; i += 128) ql[i] = query[(size_t)b * QSn + i];
    __syncthreads();
    const int u = quad * 128 + tid;
    const float* w = Wq + (size_t)u * QSn;
    float a0 = 0.f, a1 = 0.f;
    #pragma unroll 4
    for (int k = 0; k < QSn; k += 8) {
        float4 w0 = *(const float4*)(w + k);
        float4 w1 = *(const float4*)(w + k + 4);
        float4 q0 = *(const float4*)(ql + k);
        float4 q1 = *(const float4*)(ql + k + 4);
        a0 += w0.x * q0.x + w0.y * q0.y + w0.z * q0.z + w0.w * q0.w;
        a1 += w1.x * q1.x + w1.y * q1.y + w1.z * q1.z + w1.w * q1.w;
    }
    pq[(size_t)b * Un + u] = a0 + a1;
}

// ---------------- fused score+softmax+context (v20: all-bf16 all-GLOAD) -----
// Block = (b, 64-t chunk), 512 thr = 8 waves, wave w owns u [w*64, w*64+64):
// acc[2][2] = 64 AGPR.
// A: keysB bf16 64t x 32k (4 KB/kt) via GLOAD, staged by waves 0-3 (1 KB
//    each), 3-BUFFER RING: writer of ring[(kt+1)%3] issues at kt-head; its
//    last readers ran at kt-2 and are provably done (they passed barrier(kt-1)
//    with their lgkm drained by MFMA data-dependence). WAR-safe across skew.
// B: Wm bf16 wave-private dbuf (R16-verbatim zero-conflict swizzle).
// Per kt: issue {A(kt+1) [w<4], B(kt+1)x4} -> per-wave counted vmcnt(5|4)
// -> lgkm0 -> s_barrier -> 8 ds_read_b128 + 8 MFMA. NOTHING else in loop.
__global__ __launch_bounds__(512, 4) void fused_kernel(const unsigned short* __restrict__ keysB,
                                                       const unsigned short* __restrict__ WmB,
                                                       const float* __restrict__ pq,
                                                       const float* __restrict__ Wa,
                                                       float* __restrict__ score_out,
                                                       float* __restrict__ pm,
                                                       float* __restrict__ pl,
                                                       float* __restrict__ pctx) {
    __shared__ __align__(16) unsigned short Ah[3][TCH * 32];    // 12 KB ring
    __shared__ __align__(16) unsigned short Bh[2][512 * 32];    // 64 KB
    __shared__ float sc_lds[8][TCH];                            // 2 KB
    __shared__ float stot[TCH];
    __shared__ float wexp[TCH];

    const int tid = threadIdx.x;
    const int lane = tid & 63;
    const int w = tid >> 6;
    const int lc = lane & 31;
    const int l5 = lane >> 5;
    const int b = blockIdx.y;
    const int chunk = blockIdx.x;
    const int t0 = chunk * TCH;

    // shared zero-conflict rowpair swizzle (R11/R16-verified, 0 conflicts):
    // GLOAD lane l covers row2 = ((l>>3)<<1)|(bg&1), col8 = (bg>>1)*8,
    // bg = (l&7)^((l>>3)&7); dest linear l*16 B.
    const int bg = (lane & 7) ^ ((lane >> 3) & 7);
    const int srow2 = ((lane >> 3) << 1) | (bg & 1);
    const int scol8 = (bg >> 1) * 8;

    // A source (waves 0-3 only): wave w stages rows w*16 .. w*16+16
    const unsigned short* gAw = keysB +
        (size_t)(b * Tn + t0 + w * 16 + srow2) * MSn + scol8;
    // B source: wave w's private rows w*64 .. w*64+64 (4 GLOADs of 16 rows)
    const unsigned short* gBw = WmB + (size_t)(w * 64 + srow2) * MSn + scol8;

    #define STAGE_B(KT, BUF) do { \
        const unsigned short* gb_ = gBw + (KT) * 32; \
        char* bD_ = (char*)&Bh[BUF][0] + w * 4096; \
        GLOAD(gb_,                    bD_); \
        GLOAD(gb_ + (size_t)16 * MSn, bD_ + 1024); \
        GLOAD(gb_ + (size_t)32 * MSn, bD_ + 2048); \
        GLOAD(gb_ + (size_t)48 * MSn, bD_ + 3072); } while (0)

    #define STAGE_A(KT, RING) do { \
        GLOAD(gAw + (KT) * 32, (char*)&Ah[RING][0] + w * 1024); } while (0)

    f32x16 acc[2][2];
    #pragma unroll
    for (int mf = 0; mf < 2; ++mf)
        #pragma unroll
        for (int nf = 0; nf < 2; ++nf)
            #pragma unroll
            for (int r = 0; r < 16; ++r) acc[mf][nf][r] = 0.f;

    // ---- prologue: pq/Wa fully drained BEFORE any GLOAD enters the FIFO
    float pqv[2], wav[2];
    #pragma unroll
    for (int nf = 0; nf < 2; ++nf) {
        int u = w * 64 + nf * 32 + lc;
        pqv[nf] = pq[(size_t)b * Un + u];
        wav[nf] = Wa[u];
    }
    asm volatile("s_waitcnt vmcnt(0)" ::: "memory");
    SB();
    // stage kt=0: A(0)->ring0 (waves 0-3), B(0)->buf0 (all waves)
    if (w < 4) STAGE_A(0, 0);
    STAGE_B(0, 0);
    SB();

    #pragma unroll
    for (int kt = 0; kt < NKT; ++kt) {
        // issue next: A(kt+1) -> ring (kt+1)%3, B(kt+1) -> buf (kt+1)&1
        if (kt < NKT - 1) {
            if (w < 4) STAGE_A(kt + 1, (kt + 1) % 3);
            STAGE_B(kt + 1, (kt + 1) & 1);
            SB();
            // counted: drain exactly {A(kt),B(kt)}; leave the just-issued
            if (w < 4) asm volatile("s_waitcnt vmcnt(5) lgkmcnt(0)" ::: "memory");
            else       asm volatile("s_waitcnt vmcnt(4) lgkmcnt(0)" ::: "memory");
        } else {
            asm volatile("s_waitcnt vmcnt(0) lgkmcnt(0)" ::: "memory");
        }
        __builtin_amdgcn_s_barrier();
        SB();

        // ---- MFMA(kt): A from ring[kt%3] (shared), B from buf[kt&1] (private)
        {
            const unsigned short* lA = &Ah[kt % 3][0];
            const unsigned short* lB = &Bh[kt & 1][0];
            #pragma unroll
            for (int ks = 0; ks < 2; ++ks) {
                bf16x8 af[2], bfr[2];
                #pragma unroll
                for (int mf = 0; mf < 2; ++mf) {
                    int r = mf * 32 + lc;
                    int gp = (((ks * 2 + l5) << 1) | (r & 1)) ^ ((r >> 1) & 7);
                    af[mf] = *(const bf16x8*)&lA[(r >> 1) * 64 + gp * 8];
                }
                #pragma unroll
                for (int nf = 0; nf < 2; ++nf) {
                    int ru = w * 64 + nf * 32 + lc;
                    int gp = (((ks * 2 + l5) << 1) | (ru & 1)) ^ ((ru >> 1) & 7);
                    bfr[nf] = *(const bf16x8*)&lB[(ru >> 1) * 64 + gp * 8];
                }
                #pragma unroll
                for (int mf = 0; mf < 2; ++mf)
                    #pragma unroll
                    for (int nf = 0; nf < 2; ++nf)
                        acc[mf][nf] = __builtin_amdgcn_mfma_f32_32x32x16_bf16(
                            af[mf], bfr[nf], acc[mf][nf], 0, 0, 0);
            }
        }
    }
    #undef STAGE_A
    #undef STAGE_B

    // ---- epilogue: score = sum_u tanh(vals + pq[u]) * Wa[u]
    // C layout: col(u)=lc, row(t) = mf*32 + (r&3) + 8*(r>>2) + 4*l5
    #pragma unroll
    for (int mf = 0; mf < 2; ++mf) {
        #pragma unroll
        for (int r = 0; r < 16; ++r) {
            float s = tanh_fast(acc[mf][0][r] + pqv[0]) * wav[0]
                    + tanh_fast(acc[mf][1][r] + pqv[1]) * wav[1];
            s += __shfl_xor(s, 16);
            s += __shfl_xor(s, 8);
            s += __shfl_xor(s, 4);
            s += __shfl_xor(s, 2);
            s += __shfl_xor(s, 1);
            if (lc == 0)
                sc_lds[w][mf * 32 + (r & 3) + 8 * (r >> 2) + 4 * l5] = s;
        }
    }
    __syncthreads();
    if (tid < TCH) {
        float v = ((sc_lds[0][tid] + sc_lds[1][tid]) + (sc_lds[2][tid] + sc_lds[3][tid]))
                + ((sc_lds[4][tid] + sc_lds[5][tid]) + (sc_lds[6][tid] + sc_lds[7][tid]));
        stot[tid] = v;
        score_out[(size_t)b * Tn + t0 + tid] = v;
    }
    __syncthreads();

    // ---- chunk softmax partials on wave 0
    if (tid < 64) {
        float v = stot[tid];
        float mx = v;
        #pragma unroll
        for (int off = 32; off; off >>= 1) mx = fmaxf(mx, __shfl_xor(mx, off));
        float e = __expf(v - mx);
        wexp[tid] = e;
        float sum = e;
        #pragma unroll
        for (int off = 32; off; off >>= 1) sum += __shfl_xor(sum, off);
        if (tid == 0) {
            pm[b * NCH + chunk] = mx;
            pl[b * NCH + chunk] = sum;
        }
    }
    __syncthreads();

    // ---- ctx partial: thread owns 1 m-col; keysB rows re-read (L2-hot, bf16)
    const unsigned short* kp = keysB + (size_t)(b * Tn + t0) * MSn + tid;
    float cx = 0.f;
    #pragma unroll 8
    for (int t = 0; t < TCH; ++t)
        cx += wexp[t] * b2f(kp[(size_t)t * MSn]);
    pctx[((size_t)(b * NCH + chunk)) * MSn + tid] = cx;
}

// ---------------- merge chunk partials -> total_context ----------------
__global__ __launch_bounds__(512) void merge_kernel(const float* __restrict__ pm,
                                                    const float* __restrict__ pl,
                                                    const float* __restrict__ pctx,
                                                    float* __restrict__ ctx) {
    __shared__ float sm[NCH], sl[NCH];
    const int b = blockIdx.x, tid = threadIdx.x;
    if (tid < NCH) {
        sm[tid] = pm[b * NCH + tid];
        sl[tid] = pl[b * NCH + tid];
    }
    __syncthreads();
    float M = -1e30f;
    #pragma unroll
    for (int c = 0; c < NCH; ++c) M = fmaxf(M, sm[c]);
    float L = 0.f;
    #pragma unroll
    for (int c = 0; c < NCH; ++c) L += sl[c] * __expf(sm[c] - M);
    const float inv = 1.f / L;
    float acc = 0.f;
    #pragma unroll
    for (int c = 0; c < NCH; ++c)
        acc += __expf(sm[c] - M) * pctx[((size_t)(b * NCH + c)) * MSn + tid];
    ctx[(size_t)b * MSn + tid] = acc * inv;
}

extern "C" void kernel_launch(void* const* d_in, const int* in_sizes, int n_in,
                              void* d_out, int out_size, void* d_ws, size_t ws_size,
                              hipStream_t stream) {
    const float* query = (const float*)d_in[0];
    const float* keys  = (const float*)d_in[1];
    const float* Wq    = (const float*)d_in[2];
    const float* Wm    = (const float*)d_in[3];
    const float* Wa    = (const float*)d_in[4];

    float* ctx_out   = (float*)d_out;                    // [64][512]
    float* score_out = (float*)d_out + (size_t)Bn * MSn; // [64][2048]

    char* ws = (char*)d_ws;
    float* ws_pq   = (float*)(ws);                       // 128 KB
    unsigned short* ws_wmbf = (unsigned short*)(ws + 131072);  // 512 KB
    float* ws_pm   = (float*)(ws + 655360);              // 8 KB
    float* ws_pl   = (float*)(ws + 663552);              // 8 KB
    float* ws_pctx = (float*)(ws + 671744);              // 4 MB [64][32][512]
    unsigned short* ws_keysB = (unsigned short*)(ws + 4866048); // 128 MB

    cvt_kernel<<<(Un * MSn / 4) / 256, 256, 0, stream>>>(Wm, ws_wmbf);
    pq_kernel<<<dim3(Bn, 4), 128, 0, stream>>>(query, Wq, ws_pq);
    cvtkeys_kernel<<<(Bn * Tn * MSn / 8) / 256, 256, 0, stream>>>(keys, ws_keysB);
    fused_kernel<<<dim3(NCH, Bn), 512, 0, stream>>>(ws_keysB, ws_wmbf, ws_pq, Wa,
                                                    score_out, ws_pm, ws_pl, ws_pctx);
    merge_kernel<<<Bn, 512, 0, stream>>>(ws_pm, ws_pl, ws_pctx, ctx_out);
}

// Round 21
// 168.515 us; speedup vs baseline: 1.7958x; 1.2999x over previous
//
#include <hip/hip_runtime.h>
#include <cstdint>
#include <cstddef>

#define Bn 64
#define Tn 2048
#define Un 512
#define QSn 512
#define MSn 512
#define TCH 64
#define NCH 32   // chunks per batch = Tn/TCH
#define NKT 16   // K-tiles: 512 / 32

using f32x16 = __attribute__((ext_vector_type(16))) float;
using bf16x8 = __attribute__((ext_vector_type(8))) short;

__device__ __forceinline__ unsigned short f2bf(float x) {
    unsigned int u = __float_as_uint(x);
    u += 0x7FFFu + ((u >> 16) & 1u);
    return (unsigned short)(u >> 16);
}

__device__ __forceinline__ unsigned int pk2bf(float lo, float hi) {
    unsigned int r;
    asm("v_cvt_pk_bf16_f32 %0, %1, %2" : "=v"(r) : "v"(lo), "v"(hi));
    return r;
}

__device__ __forceinline__ float tanh_fast(float x) {
    float e = exp2f(x * 2.885390043258667f);   // e^{2x}
    return 1.f - 2.f * __builtin_amdgcn_rcpf(e + 1.f);
}

// async global->LDS, 16B per lane; LDS dest = wave-uniform base + lane*16
#define GLOAD(G, L) __builtin_amdgcn_global_load_lds( \
    (const __attribute__((address_space(1))) void*)(G), \
    (__attribute__((address_space(3))) void*)(L), 16, 0, 0)

#define SB() __builtin_amdgcn_sched_barrier(0)

// ---------------- Wm f32 -> bf16 pre-convert ----------------
__global__ __launch_bounds__(256) void cvt_kernel(const float* __restrict__ src,
                                                  unsigned short* __restrict__ dst) {
    int i = blockIdx.x * 256 + threadIdx.x;  // one float4 per thread
    float4 v = *(const float4*)(src + (size_t)i * 4);
    ushort4 h = { f2bf(v.x), f2bf(v.y), f2bf(v.z), f2bf(v.w) };
    *(ushort4*)&dst[(size_t)i * 4] = h;
}

// ---------------- pq = query @ Wq^T : [B,U] ----------------
__global__ __launch_bounds__(128) void pq_kernel(const float* __restrict__ query,
                                                 const float* __restrict__ Wq,
                                                 float* __restrict__ pq) {
    __shared__ float ql[QSn];
    const int b = blockIdx.x;
    const int quad = blockIdx.y;
    const int tid = threadIdx.x;
    for (int i = tid; i < QSn; i += 128) ql[i] = query[(size_t)b * QSn + i];
    __syncthreads();
    const int u = quad * 128 + tid;
    const float* w = Wq + (size_t)u * QSn;
    float a0 = 0.f, a1 = 0.f;
    #pragma unroll 4
    for (int k = 0; k < QSn; k += 8) {
        float4 w0 = *(const float4*)(w + k);
        float4 w1 = *(const float4*)(w + k + 4);
        float4 q0 = *(const float4*)(ql + k);
        float4 q1 = *(const float4*)(ql + k + 4);
        a0 += w0.x * q0.x + w0.y * q0.y + w0.z * q0.z + w0.w * q0.w;
        a1 += w1.x * q1.x + w1.y * q1.y + w1.z * q1.z + w1.w * q1.w;
    }
    pq[(size_t)b * Un + u] = a0 + a1;
}

// ---------------- fused score+softmax+context (v21: R16 + setprio) ----------
// Block = (b, 64-t chunk), 512 thr = 8 waves, wave w owns u [w*64, w*64+64):
// acc[2][2] = 64 AGPR. Best-measured schedule (R16, 167.9 us total):
//  head(kt): issue A(kt+1) flat (1 float4/thread, uniform FIFO) -> issue
//  B(kt+1) GLOADs (wave-private dbuf) -> vmcnt(5) [drains exactly B(kt),
//  leaves A(kt+1)+B(kt+1)] -> lgkmcnt(0) -> raw s_barrier -> setprio(1)
//  MFMA(kt) setprio(0) -> tail: cvt_pk + swizzled ds_write of A(kt+1)
//  (compiler-counted vmcnt(4), wave-local stall after the barrier).
// T5 setprio: with 2 barrier-groups/CU at different phases, MFMA-entering
// waves win issue slots over the other block's staging waves.
__global__ __launch_bounds__(512, 4) void fused_kernel(const float* __restrict__ keys,
                                                       const unsigned short* __restrict__ WmB,
                                                       const float* __restrict__ pq,
                                                       const float* __restrict__ Wa,
                                                       float* __restrict__ score_out,
                                                       float* __restrict__ pm,
                                                       float* __restrict__ pl,
                                                       float* __restrict__ pctx) {
    __shared__ __align__(16) unsigned short Ah[2][TCH * 32];    // 8 KB
    __shared__ __align__(16) unsigned short Bh[2][512 * 32];    // 64 KB
    __shared__ float sc_lds[8][TCH];                            // 2 KB
    __shared__ float stot[TCH];
    __shared__ float wexp[TCH];

    const int tid = threadIdx.x;
    const int lane = tid & 63;
    const int w = tid >> 6;
    const int lc = lane & 31;
    const int l5 = lane >> 5;
    const int b = blockIdx.y;
    const int chunk = blockIdx.x;
    const int t0 = chunk * TCH;

    // ---- A staging: ALL 512 threads, 1 float4 each (row ar, k-quad kq)
    const int ar = tid >> 3;          // 0..63
    const int kq = tid & 7;           // 4 f32 at k = kq*4
    const int awof = (ar >> 1) * 64 +
                     (((((kq >> 1) << 1) | (ar & 1)) ^ ((ar >> 1) & 7)) * 8) +
                     (kq & 1) * 4;
    const float* gA = keys + ((size_t)b * Tn + t0 + ar) * MSn + kq * 4;

    // ---- B staging source (R11/R15-verbatim zero-conflict swizzle)
    const int bg = (lane & 7) ^ ((lane >> 3) & 7);
    const unsigned short* gBw = WmB +
        (size_t)(w * 64 + (((lane >> 3) << 1) | (bg & 1))) * MSn + (bg >> 1) * 8;

    #define STAGE_B(KT, BUF) do { \
        const unsigned short* gb_ = gBw + (KT) * 32; \
        char* bD_ = (char*)&Bh[BUF][0] + w * 4096; \
        GLOAD(gb_,                    bD_); \
        GLOAD(gb_ + (size_t)16 * MSn, bD_ + 1024); \
        GLOAD(gb_ + (size_t)32 * MSn, bD_ + 2048); \
        GLOAD(gb_ + (size_t)48 * MSn, bD_ + 3072); } while (0)

    f32x16 acc[2][2];
    #pragma unroll
    for (int mf = 0; mf < 2; ++mf)
        #pragma unroll
        for (int nf = 0; nf < 2; ++nf)
            #pragma unroll
            for (int r = 0; r < 16; ++r) acc[mf][nf][r] = 0.f;

    // ---- prologue: pq/Wa regs; A(0); B(0); cvt+write A(0)
    float pqv[2], wav[2];
    #pragma unroll
    for (int nf = 0; nf < 2; ++nf) {
        int u = w * 64 + nf * 32 + lc;
        pqv[nf] = pq[(size_t)b * Un + u];
        wav[nf] = Wa[u];
    }
    SB();
    {
        float4 p = *(const float4*)(gA);
        SB();
        STAGE_B(0, 0);
        SB();
        uint2 h;
        h.x = pk2bf(p.x, p.y);
        h.y = pk2bf(p.z, p.w);
        *(uint2*)&Ah[0][awof] = h;   // compiler auto-waits A(0); B(0) stays out
    }

    #pragma unroll
    for (int kt = 0; kt < NKT; ++kt) {
        float4 p;
        if (kt < NKT - 1) {
            // head: issue A(kt+1) then B(kt+1)  (FIFO: [B(kt)4, A+1, B+1 x4])
            p = *(const float4*)(gA + (kt + 1) * 32);
            SB();
            STAGE_B(kt + 1, (kt + 1) & 1);
            SB();
            asm volatile("s_waitcnt vmcnt(5) lgkmcnt(0)" ::: "memory");  // B(kt) landed
        } else {
            asm volatile("s_waitcnt vmcnt(0) lgkmcnt(0)" ::: "memory");  // B(15) landed
        }
        __builtin_amdgcn_s_barrier();   // Ah[kt&1] writes visible; NO vm drain
        SB();

        // ---- MFMA(kt): Ah[kt&1] shared, Bh[kt&1] wave-private rows
        __builtin_amdgcn_s_setprio(1);
        {
            const unsigned short* lA = &Ah[kt & 1][0];
            const unsigned short* lB = &Bh[kt & 1][0];
            #pragma unroll
            for (int ks = 0; ks < 2; ++ks) {
                bf16x8 af[2], bfr[2];
                #pragma unroll
                for (int mf = 0; mf < 2; ++mf) {
                    int r = mf * 32 + lc;
                    int gp = (((ks * 2 + l5) << 1) | (r & 1)) ^ ((r >> 1) & 7);
                    af[mf] = *(const bf16x8*)&lA[(r >> 1) * 64 + gp * 8];
                }
                #pragma unroll
                for (int nf = 0; nf < 2; ++nf) {
                    int ru = w * 64 + nf * 32 + lc;
                    int gp = (((ks * 2 + l5) << 1) | (ru & 1)) ^ ((ru >> 1) & 7);
                    bfr[nf] = *(const bf16x8*)&lB[(ru >> 1) * 64 + gp * 8];
                }
                #pragma unroll
                for (int mf = 0; mf < 2; ++mf)
                    #pragma unroll
                    for (int nf = 0; nf < 2; ++nf)
                        acc[mf][nf] = __builtin_amdgcn_mfma_f32_32x32x16_bf16(
                            af[mf], bfr[nf], acc[mf][nf], 0, 0, 0);
            }
        }
        __builtin_amdgcn_s_setprio(0);
        SB();

        // tail: cvt + swizzled write A(kt+1) into the other Ah buffer.
        // (wave-local auto vmcnt(4) here; WAR safe: that buffer's readers
        // finished lgkm before they passed THIS kt's barrier.)
        if (kt < NKT - 1) {
            uint2 h;
            h.x = pk2bf(p.x, p.y);
            h.y = pk2bf(p.z, p.w);
            *(uint2*)&Ah[(kt + 1) & 1][awof] = h;
        }
    }
    #undef STAGE_B

    // ---- epilogue: score = sum_u tanh(vals + pq[u]) * Wa[u]
    // C layout: col(u)=lc, row(t) = mf*32 + (r&3) + 8*(r>>2) + 4*l5
    #pragma unroll
    for (int mf = 0; mf < 2; ++mf) {
        #pragma unroll
        for (int r = 0; r < 16; ++r) {
            float s = tanh_fast(acc[mf][0][r] + pqv[0]) * wav[0]
                    + tanh_fast(acc[mf][1][r] + pqv[1]) * wav[1];
            s += __shfl_xor(s, 16);
            s += __shfl_xor(s, 8);
            s += __shfl_xor(s, 4);
            s += __shfl_xor(s, 2);
            s += __shfl_xor(s, 1);
            if (lc == 0)
                sc_lds[w][mf * 32 + (r & 3) + 8 * (r >> 2) + 4 * l5] = s;
        }
    }
    __syncthreads();
    if (tid < TCH) {
        float v = ((sc_lds[0][tid] + sc_lds[1][tid]) + (sc_lds[2][tid] + sc_lds[3][tid]))
                + ((sc_lds[4][tid] + sc_lds[5][tid]) + (sc_lds[6][tid] + sc_lds[7][tid]));
        stot[tid] = v;
        score_out[(size_t)b * Tn + t0 + tid] = v;
    }
    __syncthreads();

    // ---- chunk softmax partials on wave 0
    if (tid < 64) {
        float v = stot[tid];
        float mx = v;
        #pragma unroll
        for (int off = 32; off; off >>= 1) mx = fmaxf(mx, __shfl_xor(mx, off));
        float e = __expf(v - mx);
        wexp[tid] = e;
        float sum = e;
        #pragma unroll
        for (int off = 32; off; off >>= 1) sum += __shfl_xor(sum, off);
        if (tid == 0) {
            pm[b * NCH + chunk] = mx;
            pl[b * NCH + chunk] = sum;
        }
    }
    __syncthreads();

    // ---- ctx partial: thread owns 1 m-col; keys rows re-read (L2/L3-hot)
    const float* kp = keys + ((size_t)b * Tn + t0) * MSn + tid;
    float cx = 0.f;
    #pragma unroll 8
    for (int t = 0; t < TCH; ++t)
        cx += wexp[t] * kp[(size_t)t * MSn];
    pctx[((size_t)(b * NCH + chunk)) * MSn + tid] = cx;
}

// ---------------- merge chunk partials -> total_context ----------------
__global__ __launch_bounds__(512) void merge_kernel(const float* __restrict__ pm,
                                                    const float* __restrict__ pl,
                                                    const float* __restrict__ pctx,
                                                    float* __restrict__ ctx) {
    __shared__ float sm[NCH], sl[NCH];
    const int b = blockIdx.x, tid = threadIdx.x;
    if (tid < NCH) {
        sm[tid] = pm[b * NCH + tid];
        sl[tid] = pl[b * NCH + tid];
    }
    __syncthreads();
    float M = -1e30f;
    #pragma unroll
    for (int c = 0; c < NCH; ++c) M = fmaxf(M, sm[c]);
    float L = 0.f;
    #pragma unroll
    for (int c = 0; c < NCH; ++c) L += sl[c] * __expf(sm[c] - M);
    const float inv = 1.f / L;
    float acc = 0.f;
    #pragma unroll
    for (int c = 0; c < NCH; ++c)
        acc += __expf(sm[c] - M) * pctx[((size_t)(b * NCH + c)) * MSn + tid];
    ctx[(size_t)b * MSn + tid] = acc * inv;
}

extern "C" void kernel_launch(void* const* d_in, const int* in_sizes, int n_in,
                              void* d_out, int out_size, void* d_ws, size_t ws_size,
                              hipStream_t stream) {
    const float* query = (const float*)d_in[0];
    const float* keys  = (const float*)d_in[1];
    const float* Wq    = (const float*)d_in[2];
    const float* Wm    = (const float*)d_in[3];
    const float* Wa    = (const float*)d_in[4];

    float* ctx_out   = (float*)d_out;                    // [64][512]
    float* score_out = (float*)d_out + (size_t)Bn * MSn; // [64][2048]

    char* ws = (char*)d_ws;
    float* ws_pq   = (float*)(ws);                       // 128 KB
    unsigned short* ws_wmbf = (unsigned short*)(ws + 131072);  // 512 KB
    float* ws_pm   = (float*)(ws + 655360);              // 8 KB
    float* ws_pl   = (float*)(ws + 663552);              // 8 KB
    float* ws_pctx = (float*)(ws + 671744);              // 4 MB [64][32][512]

    cvt_kernel<<<(Un * MSn / 4) / 256, 256, 0, stream>>>(Wm, ws_wmbf);
    pq_kernel<<<dim3(Bn, 4), 128, 0, stream>>>(query, Wq, ws_pq);
    fused_kernel<<<dim3(NCH, Bn), 512, 0, stream>>>(keys, ws_wmbf, ws_pq, Wa,
                                                    score_out, ws_pm, ws_pl, ws_pctx);
    merge_kernel<<<Bn, 512, 0, stream>>>(ws_pm, ws_pl, ws_pctx, ctx_out);
}